// Round 26
// baseline (47.453 us; speedup 1.0000x reference)
//
#include <hip/hip_runtime.h>

#define NC 32     // num_capsule
#define DC 16     // dim_capsule
#define INC 144   // input capsules
#define IND 8     // input dim
#define NT 1024   // threads: (b 0..31) x (half 0..1) x (cg 0..15); 16 waves = 4/SIMD
#define LG_S 152  // halves per b row of logits

// LDS (halves): hatL[32][144][8] | pad | hatH[32][144][8] | lg[32][152] (x overlaps lg) | o_buf[32][16]
// hat rows THREAD-PRIVATE (owner-only) -> no hat barriers, conflict-light b128 rows.
#define HATL_OFF 0
#define HATH_OFF (NC * INC * IND + 8)          // 36872; 16B-aligned
#define LG_OFF (HATH_OFF + NC * INC * IND)     // 73736; 16B-aligned
#define OB_OFF (LG_OFF + NC * LG_S)            // 78600; 16B-aligned
#define SMEM_HALVES (OB_OFF + NC * DC)         // 79112
#define SMEM_BYTES (SMEM_HALVES * 2)           // 158224 <= 163840

typedef _Float16 h2 __attribute__((ext_vector_type(2)));
typedef _Float16 h4v __attribute__((ext_vector_type(4)));
typedef _Float16 h8 __attribute__((ext_vector_type(8)));
typedef float f4 __attribute__((ext_vector_type(4)));

union H8 { h8 v; h2 p[4]; _Float16 e[8]; };
union WU { uint4 u; h8 v; h2 p[4]; };

#if __has_builtin(__builtin_amdgcn_fdot2)
__device__ __forceinline__ float fdot2(h2 a, h2 b, float c) {
    return __builtin_amdgcn_fdot2(a, b, c, false);
}
#else
__device__ __forceinline__ float fdot2(h2 a, h2 b, float c) {
    return c + (float)a[0] * (float)b[0] + (float)a[1] * (float)b[1];
}
#endif

// Convert+TRANSPOSE W: fp32 [b][c][d][i] -> fp16 h8-slots [(b*9+k)*16+d][cg],
// c = cg + 16k. 73728 h8 slots -> grid 288 x 256.
__global__ void convw_kernel(const float* __restrict__ W, _Float16* __restrict__ Wh) {
    int i = blockIdx.x * 256 + threadIdx.x;          // h8 slot 0..73727
    int cg = i & 15, d = (i >> 4) & 15, bk = i >> 8; // bk = b*9+k, 0..287
    int k = bk % 9, b = bk / 9;
    const float* s = W + (((size_t)b * INC + cg + 16 * k) * DC + d) * IND;
    f4 v0 = *reinterpret_cast<const f4*>(s);
    f4 v1 = *reinterpret_cast<const f4*>(s + 4);
    H8 o;
    o.e[0] = (_Float16)v0[0]; o.e[1] = (_Float16)v0[1];
    o.e[2] = (_Float16)v0[2]; o.e[3] = (_Float16)v0[3];
    o.e[4] = (_Float16)v1[0]; o.e[5] = (_Float16)v1[1];
    o.e[6] = (_Float16)v1[2]; o.e[7] = (_Float16)v1[3];
    *reinterpret_cast<h8*>(Wh + (size_t)i * 8) = o.v;
}

#define R8(M)  M(0) M(1) M(2) M(3) M(4) M(5) M(6) M(7)
#define R9(M)  M(0) M(1) M(2) M(3) M(4) M(5) M(6) M(7) M(8)
#define R16(M) M(0) M(1) M(2) M(3) M(4) M(5) M(6) M(7) M(8) M(9) M(10) M(11) M(12) M(13) M(14) M(15)

template <typename WT>
__global__ __launch_bounds__(NT, 4)  // 16 waves = 1 block/CU; demand ~50 < 64 budget
void caps_kernel(const float* __restrict__ xg, const WT* __restrict__ Wg,
                 float* __restrict__ out) {
    extern __shared__ __align__(16) _Float16 sm[];
    _Float16* lg = sm + LG_OFF;
    _Float16* o_buf = sm + OB_OFF;
    _Float16* x_h = lg;  // overlap: x only live during phase H (barrier before lg use)

    const int t = threadIdx.x;
    const int cg = t & 15;         // c-group: owns c = cg + 16k
    const int half = (t >> 4) & 1; // d-half: owns d = half*8 + 0..7
    const int b = t >> 5;          // capsule
    const int a = blockIdx.x;

    // ---- load x[a]: 1152 floats = 288 f4 -> fp16 LDS ----
    if (t < 288) {
        f4 v = reinterpret_cast<const f4*>(xg + (size_t)a * (INC * IND))[t];
        h4v hv;
        hv[0] = (_Float16)v[0]; hv[1] = (_Float16)v[1];
        hv[2] = (_Float16)v[2]; hv[3] = (_Float16)v[3];
        *reinterpret_cast<h4v*>(x_h + t * 4) = hv;
    }
    __syncthreads();

    _Float16* hbase = sm + (half ? HATH_OFF : HATL_OFF);  // owner-private rows

#define DECLS(D) float s##D;
    R8(DECLS)
#define ZEROS(D) s##D = 0.f;
    R8(ZEROS)

    // one d of one c: 16B W load + 4-chain fdot2; pack + accumulate s_d
#define HD1(T, E) { \
    WU w; w.u = *reinterpret_cast<const uint4*>(wrb + (E) * 256); \
    float ac = fdot2(w.p[0], xv.p[0], 0.f); \
    ac = fdot2(w.p[1], xv.p[1], ac); \
    ac = fdot2(w.p[2], xv.p[2], ac); \
    ac = fdot2(w.p[3], xv.p[3], ac); \
    T.e[E] = (_Float16)ac; s##E += ac; }

    // float-W fallback
#define HD1F(T, E) { \
    const float* wf = wfr + (half * 8 + (E)) * IND; \
    f4 w0 = *reinterpret_cast<const f4*>(wf); \
    f4 w1 = *reinterpret_cast<const f4*>(wf + 4); \
    float ac = (float)xv.e[0] * w0[0]; \
    ac = fmaf((float)xv.e[1], w0[1], ac); \
    ac = fmaf((float)xv.e[2], w0[2], ac); \
    ac = fmaf((float)xv.e[3], w0[3], ac); \
    ac = fmaf((float)xv.e[4], w1[0], ac); \
    ac = fmaf((float)xv.e[5], w1[1], ac); \
    ac = fmaf((float)xv.e[6], w1[2], ac); \
    ac = fmaf((float)xv.e[7], w1[3], ac); \
    T.e[E] = (_Float16)ac; s##E += ac; }

    // Phase H: hat[b][c][half*8..+7] for own 9 c's -> private LDS rows (b128)
#define HSTEP(K) { \
    const int c = cg + 16 * (K); \
    H8 xv; xv.v = *reinterpret_cast<const h8*>(x_h + c * IND); \
    H8 tV; \
    if constexpr (sizeof(WT) == 2) { \
        const char* wrb = reinterpret_cast<const char*>(Wg) + \
                          (size_t)(b * 9 + (K)) * 4096 + half * 2048 + cg * 16; \
        HD1(tV,0) HD1(tV,1) HD1(tV,2) HD1(tV,3) \
        HD1(tV,4) HD1(tV,5) HD1(tV,6) HD1(tV,7) \
    } else { \
        const float* wfr = reinterpret_cast<const float*>(Wg) + \
                           (size_t)(b * INC + c) * (DC * IND); \
        HD1F(tV,0) HD1F(tV,1) HD1F(tV,2) HD1F(tV,3) \
        HD1F(tV,4) HD1F(tV,5) HD1F(tV,6) HD1F(tV,7) \
    } \
    *reinterpret_cast<h8*>(hbase + (size_t)(b * INC + c) * 8) = tV.v; }

    R9(HSTEP)
    __syncthreads();  // x_h reads done everywhere before B-pass writes lg (overlap)

    // ---- 8-value recursive-halving transpose-reduce over the 16 cg lanes:
    // lane cg ends with FULL sum of d-index (cg>>1) (pair-duplicated).
    const bool c8 = (cg & 8) != 0, c4 = (cg & 4) != 0, c2 = (cg & 2) != 0;
#define HV(A, B, M, CB) { float snd_ = (CB) ? s##A : s##B; \
                          float kp_ = (CB) ? s##B : s##A; \
                          s##A = kp_ + __shfl_xor(snd_, M, 16); }
#define HALVE8 \
    HV(0,4,8,c8) HV(1,5,8,c8) HV(2,6,8,c8) HV(3,7,8,c8) \
    HV(0,2,4,c4) HV(1,3,4,c4) \
    HV(0,1,2,c2) \
    s0 += __shfl_xor(s0, 1, 16);

    // squash from distributed s: n2 butterfly over masks 2/4/8 (distinct
    // values only -- lane pairs hold duplicates) + one cross-half shuffle.
#define SQUASH1(RS, OVAL) \
    float r_ = s0 * (RS); \
    float n2_ = r_ * r_; \
    n2_ += __shfl_xor(n2_, 2, 16); n2_ += __shfl_xor(n2_, 4, 16); \
    n2_ += __shfl_xor(n2_, 8, 16); \
    n2_ += __shfl_xor(n2_, 16, 32);  /* other d-half */ \
    float OVAL = r_ * (n2_ / ((1.0f + n2_) * sqrtf(n2_ + 1e-7f)));

    // rebuild this thread's o half-vector via same-wave LDS broadcast
#define OBCAST(OVAL) \
    if ((cg & 1) == 0) o_buf[b * DC + half * 8 + (cg >> 1)] = (_Float16)(OVAL); \
    __threadfence_block(); \
    oV = *reinterpret_cast<const h8*>(o_buf + b * DC + half * 8);

    h8 oV;
    HALVE8
    {
        SQUASH1(1.0f / 32.0f, oval)  // softmax(0) uniform coefficients
        OBCAST(oval)
    }

#define DECLG(K) float lgr##K = 0.f;
    R9(DECLG)

    // B-pass: half-dot over own 8 d's + one cross-half width-32 shuffle
#define BSTEP(K) { \
    const int c = cg + 16 * (K); \
    H8 hv; hv.v = *reinterpret_cast<const h8*>(hbase + (size_t)(b * INC + c) * 8); \
    H8 ov; ov.v = oV; \
    float dt  = fdot2(hv.p[0], ov.p[0], 0.f); \
    float dt2 = fdot2(hv.p[1], ov.p[1], 0.f); \
    dt  = fdot2(hv.p[2], ov.p[2], dt); \
    dt2 = fdot2(hv.p[3], ov.p[3], dt2); \
    dt += dt2; \
    dt += __shfl_xor(dt, 16, 32); \
    lgr##K += dt; \
    lg[b * LG_S + c] = (_Float16)lgr##K; }

    // S-pass: s_d += cc[b][c] * hat[c][d] over own 9 c's x 8 d's
#define SSTEP(K) { \
    const int c = cg + 16 * (K); \
    float cf = (float)lg[b * LG_S + c]; \
    H8 hv; hv.v = *reinterpret_cast<const h8*>(hbase + (size_t)(b * INC + c) * 8); \
    s0 = fmaf(cf, (float)hv.e[0], s0); s1 = fmaf(cf, (float)hv.e[1], s1); \
    s2 = fmaf(cf, (float)hv.e[2], s2); s3 = fmaf(cf, (float)hv.e[3], s3); \
    s4 = fmaf(cf, (float)hv.e[4], s4); s5 = fmaf(cf, (float)hv.e[5], s5); \
    s6 = fmaf(cf, (float)hv.e[6], s6); s7 = fmaf(cf, (float)hv.e[7], s7); }

    for (int it = 0; it < 2; ++it) {
        R9(BSTEP)
        __syncthreads();

        // softmax over 32 capsules: 2 threads per c, 16 bb's each, named regs
        if (t < 2 * INC) {
            const int c = t >> 1;
            const int rb = (t & 1) * 16;
#define SMR(I) float v##I = (float)lg[(rb + I) * LG_S + c];
            R16(SMR)
            float m = fmaxf(v0, v1);
#define SMM(I) m = fmaxf(m, v##I);
            SMM(2) SMM(3) SMM(4) SMM(5) SMM(6) SMM(7) SMM(8) SMM(9)
            SMM(10) SMM(11) SMM(12) SMM(13) SMM(14) SMM(15)
            m = fmaxf(m, __shfl_xor(m, 1));
            float S = 0.f;
#define SME(I) v##I = __expf(v##I - m); S += v##I;
            R16(SME)
            S += __shfl_xor(S, 1);
            float inv = 1.0f / S;
#define SMW(I) lg[(rb + I) * LG_S + c] = (_Float16)(v##I * inv);
            R16(SMW)
        }
        __syncthreads();

        R8(ZEROS)
        R9(SSTEP)
        HALVE8

        if (it == 0) {
            SQUASH1(1.0f, oval)
            OBCAST(oval)
            __syncthreads();  // S-reads of lg done before next B-pass writes
        } else {
            SQUASH1(1.0f, oval)
            if ((cg & 1) == 0)  // lane pairs hold duplicates; even lanes write
                out[(size_t)a * (NC * DC) + b * DC + half * 8 + (cg >> 1)] = oval;
        }
    }
}

extern "C" void kernel_launch(void* const* d_in, const int* in_sizes, int n_in,
                              void* d_out, int out_size, void* d_ws, size_t ws_size,
                              hipStream_t stream) {
    const float* x = (const float*)d_in[0];
    const float* W = (const float*)d_in[1];
    float* out = (float*)d_out;

    const size_t WH_BYTES = (size_t)NC * INC * DC * IND * 2;  // 1179648

    if (ws_size >= WH_BYTES) {
        _Float16* Wh = (_Float16*)d_ws;
        hipLaunchKernelGGL(convw_kernel, dim3(288), dim3(256), 0, stream, W, Wh);
        hipFuncSetAttribute(reinterpret_cast<const void*>(&caps_kernel<_Float16>),
                            hipFuncAttributeMaxDynamicSharedMemorySize, SMEM_BYTES);
        hipLaunchKernelGGL(caps_kernel<_Float16>, dim3(512), dim3(NT), SMEM_BYTES,
                           stream, x, Wh, out);
    } else {
        hipFuncSetAttribute(reinterpret_cast<const void*>(&caps_kernel<float>),
                            hipFuncAttributeMaxDynamicSharedMemorySize, SMEM_BYTES);
        hipLaunchKernelGGL(caps_kernel<float>, dim3(512), dim3(NT), SMEM_BYTES,
                           stream, x, W, out);
    }
}